// Round 10
// baseline (924.195 us; speedup 1.0000x reference)
//
#include <hip/hip_runtime.h>
#include <hip/hip_bf16.h>

typedef __attribute__((ext_vector_type(8))) _Float16 h8v;
typedef __attribute__((ext_vector_type(4))) float f4v;

__device__ __forceinline__ ushort f16bits(float f) {
    _Float16 h = (_Float16)f;
    return __builtin_bit_cast(unsigned short, h);
}

// ---------------- gate: alpha = softmax(x @ gate_W + gate_b) ----------------
__global__ __launch_bounds__(256) void gate_kernel(
    const float* __restrict__ x, const float* __restrict__ gW,
    const float* __restrict__ gb, float* __restrict__ alpha)
{
    int lane = threadIdx.x & 63;
    int wave = threadIdx.x >> 6;
    int row = blockIdx.x * 4 + wave;
    float4 xv = *(const float4*)(x + (size_t)row * 256 + lane * 4);
    const float* xp = (const float*)&xv;
    float p[8];
#pragma unroll
    for (int k = 0; k < 8; ++k) p[k] = 0.f;
#pragma unroll
    for (int j = 0; j < 4; ++j) {
        float xs = xp[j];
        const float* wr = gW + (lane * 4 + j) * 8;
#pragma unroll
        for (int k = 0; k < 8; ++k) p[k] = fmaf(xs, wr[k], p[k]);
    }
#pragma unroll
    for (int off = 32; off > 0; off >>= 1) {
#pragma unroll
        for (int k = 0; k < 8; ++k) p[k] += __shfl_xor(p[k], off);
    }
    float m = -1e30f;
#pragma unroll
    for (int k = 0; k < 8; ++k) { p[k] += gb[k]; m = fmaxf(m, p[k]); }
    float s = 0.f;
#pragma unroll
    for (int k = 0; k < 8; ++k) { p[k] = expf(p[k] - m); s += p[k]; }
    if (lane < 8) alpha[(size_t)row * 8 + lane] = p[lane] / s;
}

// ---- weight prep: retile to [layer][e][kgroup][o][32k'] fp16 (R5 layout) --
// One block per (mat m 0..39, kgroup g 0..7). Thread o handles one output
// column: reads 32 K-values, writes 64B contiguous. GEMM fragment loads
// become lane-contiguous 1KB blocks per (in) -> perfectly coalesced.
__global__ __launch_bounds__(256) void prep_weights(
    const float* __restrict__ blockW, const float* __restrict__ outW,
    ushort* __restrict__ Wg)
{
    const int m = blockIdx.x >> 3;
    const int g = blockIdx.x & 7;
    const float* src = (m < 32) ? (blockW + (size_t)m * 65536)
                                : (outW + (size_t)(m - 32) * 65536);
    const int o = threadIdx.x;
    uint pk[16];
#pragma unroll
    for (int kp = 0; kp < 16; ++kp) {
        float f0 = src[(size_t)(g * 32 + 2 * kp) * 256 + o];
        float f1 = src[(size_t)(g * 32 + 2 * kp + 1) * 256 + o];
        pk[kp] = (uint)f16bits(f0) | ((uint)f16bits(f1) << 16);
    }
    size_t base = (size_t)(m >> 3) * 524288 + (size_t)((m & 7) * 8 + g) * 8192
                + (size_t)o * 32;
    *(uint4*)(Wg + base)      = make_uint4(pk[0],  pk[1],  pk[2],  pk[3]);
    *(uint4*)(Wg + base + 8)  = make_uint4(pk[4],  pk[5],  pk[6],  pk[7]);
    *(uint4*)(Wg + base + 16) = make_uint4(pk[8],  pk[9],  pk[10], pk[11]);
    *(uint4*)(Wg + base + 24) = make_uint4(pk[12], pk[13], pk[14], pk[15]);
}

// ------------- fused MoIE layer, barrier-free K-loop -----------------------
// BM=128, BN=256 (full width -> in-place safe), 1024 thr = 16 waves (4x4),
// wave tile 32x64 (acc=32 VGPR). A tile (128x256 fp16) in LDS (64 KB),
// staged once + ONE __syncthreads. B fragments stream global->registers
// (L1/L2-resident weights, coalesced frag layout), double-buffered 1 tile
// ahead. Alpha static-indexed packed fp16 (e fully unrolled). No barriers
// in the loop: 16 waves/CU free-run and self-stagger.
// MODE: 0 = f32 in / f16 out (relu), 1 = f16/f16 (relu), 2 = f16/f32 (none)
template<int MODE>
__global__ __launch_bounds__(1024, 4) void moie_gemm(
    const void* __restrict__ HinV, ushort* __restrict__ Hout16,
    float* __restrict__ HoutF,
    const ushort* __restrict__ Wg, const float* __restrict__ bias,
    const float* __restrict__ alpha)
{
    __shared__ __align__(16) ushort Ah[128 * 256];    // 64 KB, swizzled

    const int tid  = threadIdx.x;
    const int lane = tid & 63;
    const int wid  = tid >> 6;      // 0..15
    const int wr   = wid >> 2;      // 0..3
    const int wc   = wid & 3;       // 0..3
    const int m0   = blockIdx.x * 128;
    const int wrow0 = wr * 32;
    const int wcol0 = wc * 64;
    const int kgl = lane >> 4;      // 0..3
    const int fr  = lane & 15;

    // ---- alpha -> packed fp16, statically indexed only (8 VGPR) ----
    _Float16 ah[2][8];
#pragma unroll
    for (int im = 0; im < 2; ++im) {
        const float4* ap = (const float4*)(alpha + (size_t)(m0 + wrow0 + im * 16 + fr) * 8);
        float4 a0 = ap[0], a1 = ap[1];
        ah[im][0] = (_Float16)a0.x; ah[im][1] = (_Float16)a0.y;
        ah[im][2] = (_Float16)a0.z; ah[im][3] = (_Float16)a0.w;
        ah[im][4] = (_Float16)a1.x; ah[im][5] = (_Float16)a1.y;
        ah[im][6] = (_Float16)a1.z; ah[im][7] = (_Float16)a1.w;
    }

    // ---- stage A tile: H[m0+r][k] -> fp16 LDS, swizzle kg ^= (row&7) ----
    {
        const int r0  = tid >> 6;         // 0..15
        const int kk  = (tid & 63) * 4;   // 0..252
        const int kg  = kk >> 3;
        const int klo = kk & 7;           // 0 or 4
#pragma unroll
        for (int p = 0; p < 8; ++p) {
            int row = p * 16 + r0;
            uint2 pk;
            if (MODE == 0) {
                const float* Hf = (const float*)HinV;
                float4 v = *(const float4*)(Hf + (size_t)(m0 + row) * 256 + kk);
                pk.x = (uint)f16bits(v.x) | ((uint)f16bits(v.y) << 16);
                pk.y = (uint)f16bits(v.z) | ((uint)f16bits(v.w) << 16);
            } else {
                const ushort* Hh = (const ushort*)HinV;
                pk = *(const uint2*)(Hh + (size_t)(m0 + row) * 256 + kk);
            }
            *(uint2*)&Ah[row * 256 + (kg ^ (row & 7)) * 8 + klo] = pk;
        }
    }
    __syncthreads();   // publish A; ONLY barrier in the kernel

    // ---- B fragment base: tile phys = e*8+ki (8192 ushorts each) ----
    const ushort* Wslice = Wg + (size_t)(wcol0 + fr) * 32 + kgl * 8;

    f4v acc[2][4];
#pragma unroll
    for (int a = 0; a < 2; ++a)
#pragma unroll
        for (int b = 0; b < 4; ++b) acc[a][b] = (f4v){0.f, 0.f, 0.f, 0.f};

    // prologue: prefetch tile (e=0, ki=0)
    h8v bcur[4], bnxt[4];
#pragma unroll
    for (int in = 0; in < 4; ++in)
        bcur[in] = *(const h8v*)(Wslice + in * 512);

#pragma unroll 1
    for (int ki = 0; ki < 8; ++ki) {
        // A frags for this K-group (shared LDS, read-only)
        h8v afc[2];
        const int kg0 = ki * 4;
#pragma unroll
        for (int im = 0; im < 2; ++im) {
            int row = wrow0 + im * 16 + fr;
            afc[im] = *(const h8v*)&Ah[row * 256 + ((kg0 + kgl) ^ (row & 7)) * 8];
        }
#pragma unroll
        for (int e = 0; e < 8; ++e) {   // fully unrolled: static e
            // prefetch next tile: (e+1, ki) else (0, ki+1); clamp at end
            const int nt_e  = (e < 7) ? (e + 1) : 0;
            const int nt_ki_static = (e < 7) ? 0 : 1;   // add to ki
            int nki = ki + nt_ki_static;
            if (nki > 7) nki = 7;
            const ushort* tp = Wslice + (size_t)(nt_e * 8 + nki) * 8192;
#pragma unroll
            for (int in = 0; in < 4; ++in)
                bnxt[in] = *(const h8v*)(tp + in * 512);
            // alpha_e applied via v_pk_mul_f16 (static index -> registers)
            h8v as[2];
#pragma unroll
            for (int im = 0; im < 2; ++im)
                as[im] = afc[im] * ah[im][e];
            __builtin_amdgcn_s_setprio(1);
#pragma unroll
            for (int im = 0; im < 2; ++im)
#pragma unroll
                for (int in = 0; in < 4; ++in)
                    acc[im][in] = __builtin_amdgcn_mfma_f32_16x16x32_f16(
                        as[im], bcur[in], acc[im][in], 0, 0, 0);
            __builtin_amdgcn_s_setprio(0);
#pragma unroll
            for (int in = 0; in < 4; ++in)
                bcur[in] = bnxt[in];     // SSA rename after unroll
        }
    }

    // ---- epilogue: + sum_k alpha[b,k]*bias[k,o], relu+f16 or f32 store ----
    float bv[4][8];
#pragma unroll
    for (int in = 0; in < 4; ++in) {
        int col = wcol0 + in * 16 + fr;
#pragma unroll
        for (int k = 0; k < 8; ++k) bv[in][k] = bias[k * 256 + col];
    }
#pragma unroll
    for (int im = 0; im < 2; ++im) {
#pragma unroll
        for (int j = 0; j < 4; ++j) {
            int row = m0 + wrow0 + im * 16 + kgl * 4 + j;
            const float4* ap = (const float4*)(alpha + (size_t)row * 8);
            float4 a0 = ap[0], a1 = ap[1];
            float a8[8] = {a0.x, a0.y, a0.z, a0.w, a1.x, a1.y, a1.z, a1.w};
#pragma unroll
            for (int in = 0; in < 4; ++in) {
                int col = wcol0 + in * 16 + fr;
                float be = 0.f;
#pragma unroll
                for (int k = 0; k < 8; ++k) be = fmaf(a8[k], bv[in][k], be);
                float v = acc[im][in][j] + be;
                if (MODE == 2) {
                    HoutF[(size_t)row * 256 + col] = v;
                } else {
                    Hout16[(size_t)row * 256 + col] = f16bits(fmaxf(v, 0.f));
                }
            }
        }
    }
}

extern "C" void kernel_launch(void* const* d_in, const int* in_sizes, int n_in,
                              void* d_out, int out_size, void* d_ws, size_t ws_size,
                              hipStream_t stream)
{
    const float* x      = (const float*)d_in[0];
    const float* gW     = (const float*)d_in[1];
    const float* gb     = (const float*)d_in[2];
    const float* blockW = (const float*)d_in[3];
    const float* blockB = (const float*)d_in[4];
    const float* outW   = (const float*)d_in[5];
    const float* outB   = (const float*)d_in[6];
    float* out = (float*)d_out;

    char* ws = (char*)d_ws;
    float*  alpha = (float*)ws;                 // 1 MB
    ushort* Wg    = (ushort*)(ws + (1 << 20));  // 40*65536*2B = 5.25 MB
    ushort* H16   = (ushort*)(ws + (8 << 20));  // 16 MB intermediate H (fp16)

    prep_weights<<<320, 256, 0, stream>>>(blockW, outW, Wg);
    gate_kernel<<<8192, 256, 0, stream>>>(x, gW, gb, alpha);

    const size_t WL = (size_t)524288;   // ushorts per layer
    moie_gemm<0><<<256, 1024, 0, stream>>>(x,   H16, nullptr, Wg,          blockB,            alpha);
    moie_gemm<1><<<256, 1024, 0, stream>>>(H16, H16, nullptr, Wg + 1 * WL, blockB + 1 * 2048, alpha);
    moie_gemm<1><<<256, 1024, 0, stream>>>(H16, H16, nullptr, Wg + 2 * WL, blockB + 2 * 2048, alpha);
    moie_gemm<1><<<256, 1024, 0, stream>>>(H16, H16, nullptr, Wg + 3 * WL, blockB + 3 * 2048, alpha);
    moie_gemm<2><<<256, 1024, 0, stream>>>(H16, nullptr, out, Wg + 4 * WL, outB,              alpha);
}

// Round 11
// 370.758 us; speedup vs baseline: 2.4927x; 2.4927x over previous
//
#include <hip/hip_runtime.h>
#include <hip/hip_bf16.h>

typedef __attribute__((ext_vector_type(8))) _Float16 h8v;
typedef __attribute__((ext_vector_type(4))) float f4v;

__device__ __forceinline__ ushort f16bits(float f) {
    _Float16 h = (_Float16)f;
    return __builtin_bit_cast(unsigned short, h);
}

// ---------------- gate: alpha = softmax(x @ gate_W + gate_b) ----------------
__global__ __launch_bounds__(256) void gate_kernel(
    const float* __restrict__ x, const float* __restrict__ gW,
    const float* __restrict__ gb, float* __restrict__ alpha)
{
    int lane = threadIdx.x & 63;
    int wave = threadIdx.x >> 6;
    int row = blockIdx.x * 4 + wave;
    float4 xv = *(const float4*)(x + (size_t)row * 256 + lane * 4);
    const float* xp = (const float*)&xv;
    float p[8];
#pragma unroll
    for (int k = 0; k < 8; ++k) p[k] = 0.f;
#pragma unroll
    for (int j = 0; j < 4; ++j) {
        float xs = xp[j];
        const float* wr = gW + (lane * 4 + j) * 8;
#pragma unroll
        for (int k = 0; k < 8; ++k) p[k] = fmaf(xs, wr[k], p[k]);
    }
#pragma unroll
    for (int off = 32; off > 0; off >>= 1) {
#pragma unroll
        for (int k = 0; k < 8; ++k) p[k] += __shfl_xor(p[k], off);
    }
    float m = -1e30f;
#pragma unroll
    for (int k = 0; k < 8; ++k) { p[k] += gb[k]; m = fmaxf(m, p[k]); }
    float s = 0.f;
#pragma unroll
    for (int k = 0; k < 8; ++k) { p[k] = expf(p[k] - m); s += p[k]; }
    if (lane < 8) alpha[(size_t)row * 8 + lane] = p[lane] / s;
}

// ---- weight prep: retile to [layer][e][kgroup][o][32k'] fp16 --------------
// One block per (mat m 0..39, kgroup g 0..7). GEMM fragment loads become
// lane-contiguous 1KB blocks per (in) -> perfectly coalesced.
__global__ __launch_bounds__(256) void prep_weights(
    const float* __restrict__ blockW, const float* __restrict__ outW,
    ushort* __restrict__ Wg)
{
    const int m = blockIdx.x >> 3;
    const int g = blockIdx.x & 7;
    const float* src = (m < 32) ? (blockW + (size_t)m * 65536)
                                : (outW + (size_t)(m - 32) * 65536);
    const int o = threadIdx.x;
    uint pk[16];
#pragma unroll
    for (int kp = 0; kp < 16; ++kp) {
        float f0 = src[(size_t)(g * 32 + 2 * kp) * 256 + o];
        float f1 = src[(size_t)(g * 32 + 2 * kp + 1) * 256 + o];
        pk[kp] = (uint)f16bits(f0) | ((uint)f16bits(f1) << 16);
    }
    size_t base = (size_t)(m >> 3) * 524288 + (size_t)((m & 7) * 8 + g) * 8192
                + (size_t)o * 32;
    *(uint4*)(Wg + base)      = make_uint4(pk[0],  pk[1],  pk[2],  pk[3]);
    *(uint4*)(Wg + base + 8)  = make_uint4(pk[4],  pk[5],  pk[6],  pk[7]);
    *(uint4*)(Wg + base + 16) = make_uint4(pk[8],  pk[9],  pk[10], pk[11]);
    *(uint4*)(Wg + base + 24) = make_uint4(pk[12], pk[13], pk[14], pk[15]);
}

// ------------- fused MoIE layer, barrier-free K-loop -----------------------
// BM=64, BN=256 (full width -> in-place safe), 512 thr = 8 waves (2x4),
// wave tile 32x64 (acc=32 VGPR). A tile (64x256 fp16, 32 KB) in LDS, staged
// once + ONE __syncthreads. B streams global->registers (L1/L2-resident,
// frag-contiguous layout); e fully unrolled so compiler pipelines loads and
// alpha stays statically indexed in 8 VGPRs. ~90 VGPR total -- under the
// allocator's 128 clamp (R10 died at 64-VGPR clamp w/ 1024 thr).
// MODE: 0 = f32 in / f16 out (relu), 1 = f16/f16 (relu), 2 = f16/f32 (none)
template<int MODE>
__global__ __launch_bounds__(512, 2) void moie_gemm(
    const void* __restrict__ HinV, ushort* __restrict__ Hout16,
    float* __restrict__ HoutF,
    const ushort* __restrict__ Wg, const float* __restrict__ bias,
    const float* __restrict__ alpha)
{
    __shared__ __align__(16) ushort Ah[64 * 256];    // 32 KB, swizzled

    const int tid  = threadIdx.x;
    const int lane = tid & 63;
    const int wid  = tid >> 6;      // 0..7
    const int wr   = wid >> 2;      // 0..1
    const int wc   = wid & 3;       // 0..3
    const int m0   = blockIdx.x * 64;
    const int wrow0 = wr * 32;
    const int wcol0 = wc * 64;
    const int kgl = lane >> 4;      // 0..3
    const int fr  = lane & 15;

    // ---- alpha -> packed fp16, statically indexed only (8 VGPR) ----
    _Float16 ah[2][8];
#pragma unroll
    for (int im = 0; im < 2; ++im) {
        const float4* ap = (const float4*)(alpha + (size_t)(m0 + wrow0 + im * 16 + fr) * 8);
        float4 a0 = ap[0], a1 = ap[1];
        ah[im][0] = (_Float16)a0.x; ah[im][1] = (_Float16)a0.y;
        ah[im][2] = (_Float16)a0.z; ah[im][3] = (_Float16)a0.w;
        ah[im][4] = (_Float16)a1.x; ah[im][5] = (_Float16)a1.y;
        ah[im][6] = (_Float16)a1.z; ah[im][7] = (_Float16)a1.w;
    }

    // ---- stage A tile: H[m0+r][k] -> fp16 LDS, swizzle kg ^= (row&7) ----
    {
        const int r0  = tid >> 6;         // 0..7
        const int kk  = (tid & 63) * 4;   // 0..252
        const int kg  = kk >> 3;
        const int klo = kk & 7;           // 0 or 4
#pragma unroll
        for (int p = 0; p < 8; ++p) {
            int row = p * 8 + r0;
            uint2 pk;
            if (MODE == 0) {
                const float* Hf = (const float*)HinV;
                float4 v = *(const float4*)(Hf + (size_t)(m0 + row) * 256 + kk);
                pk.x = (uint)f16bits(v.x) | ((uint)f16bits(v.y) << 16);
                pk.y = (uint)f16bits(v.z) | ((uint)f16bits(v.w) << 16);
            } else {
                const ushort* Hh = (const ushort*)HinV;
                pk = *(const uint2*)(Hh + (size_t)(m0 + row) * 256 + kk);
            }
            *(uint2*)&Ah[row * 256 + (kg ^ (row & 7)) * 8 + klo] = pk;
        }
    }
    __syncthreads();   // publish A; ONLY barrier in the kernel

    // ---- B fragment base: tile phys = e*8+ki (8192 ushorts each) ----
    const ushort* Wslice = Wg + (size_t)(wcol0 + fr) * 32 + (size_t)kgl * 8;

    f4v acc[2][4];
#pragma unroll
    for (int a = 0; a < 2; ++a)
#pragma unroll
        for (int b = 0; b < 4; ++b) acc[a][b] = (f4v){0.f, 0.f, 0.f, 0.f};

#pragma unroll 1
    for (int ki = 0; ki < 8; ++ki) {
        // A frags for this K-group (shared LDS, read-only)
        h8v afc[2];
        const int kg0 = ki * 4;
#pragma unroll
        for (int im = 0; im < 2; ++im) {
            int row = wrow0 + im * 16 + fr;
            afc[im] = *(const h8v*)&Ah[row * 256 + ((kg0 + kgl) ^ (row & 7)) * 8];
        }
#pragma unroll
        for (int e = 0; e < 8; ++e) {   // fully unrolled: static e
            const ushort* tp = Wslice + (size_t)(e * 8 + ki) * 8192;
            h8v bf[4];
#pragma unroll
            for (int in = 0; in < 4; ++in)
                bf[in] = *(const h8v*)(tp + in * 512);
            // alpha_e applied via v_pk_mul_f16 (static index -> registers)
            h8v as[2];
#pragma unroll
            for (int im = 0; im < 2; ++im)
                as[im] = afc[im] * ah[im][e];
            __builtin_amdgcn_s_setprio(1);
#pragma unroll
            for (int im = 0; im < 2; ++im)
#pragma unroll
                for (int in = 0; in < 4; ++in)
                    acc[im][in] = __builtin_amdgcn_mfma_f32_16x16x32_f16(
                        as[im], bf[in], acc[im][in], 0, 0, 0);
            __builtin_amdgcn_s_setprio(0);
        }
    }

    // ---- epilogue: + sum_k alpha[b,k]*bias[k,o], relu+f16 or f32 store ----
    float bv[4][8];
#pragma unroll
    for (int in = 0; in < 4; ++in) {
        int col = wcol0 + in * 16 + fr;
#pragma unroll
        for (int k = 0; k < 8; ++k) bv[in][k] = bias[k * 256 + col];
    }
#pragma unroll
    for (int im = 0; im < 2; ++im) {
#pragma unroll
        for (int j = 0; j < 4; ++j) {
            int row = m0 + wrow0 + im * 16 + kgl * 4 + j;
            const float4* ap = (const float4*)(alpha + (size_t)row * 8);
            float4 a0 = ap[0], a1 = ap[1];
            float a8[8] = {a0.x, a0.y, a0.z, a0.w, a1.x, a1.y, a1.z, a1.w};
#pragma unroll
            for (int in = 0; in < 4; ++in) {
                int col = wcol0 + in * 16 + fr;
                float be = 0.f;
#pragma unroll
                for (int k = 0; k < 8; ++k) be = fmaf(a8[k], bv[in][k], be);
                float v = acc[im][in][j] + be;
                if (MODE == 2) {
                    HoutF[(size_t)row * 256 + col] = v;
                } else {
                    Hout16[(size_t)row * 256 + col] = f16bits(fmaxf(v, 0.f));
                }
            }
        }
    }
}

extern "C" void kernel_launch(void* const* d_in, const int* in_sizes, int n_in,
                              void* d_out, int out_size, void* d_ws, size_t ws_size,
                              hipStream_t stream)
{
    const float* x      = (const float*)d_in[0];
    const float* gW     = (const float*)d_in[1];
    const float* gb     = (const float*)d_in[2];
    const float* blockW = (const float*)d_in[3];
    const float* blockB = (const float*)d_in[4];
    const float* outW   = (const float*)d_in[5];
    const float* outB   = (const float*)d_in[6];
    float* out = (float*)d_out;

    char* ws = (char*)d_ws;
    float*  alpha = (float*)ws;                 // 1 MB
    ushort* Wg    = (ushort*)(ws + (1 << 20));  // 40*65536*2B = 5.25 MB
    ushort* H16   = (ushort*)(ws + (8 << 20));  // 16 MB intermediate H (fp16)

    prep_weights<<<320, 256, 0, stream>>>(blockW, outW, Wg);
    gate_kernel<<<8192, 256, 0, stream>>>(x, gW, gb, alpha);

    const size_t WL = (size_t)524288;   // ushorts per layer
    moie_gemm<0><<<512, 512, 0, stream>>>(x,   H16, nullptr, Wg,          blockB,            alpha);
    moie_gemm<1><<<512, 512, 0, stream>>>(H16, H16, nullptr, Wg + 1 * WL, blockB + 1 * 2048, alpha);
    moie_gemm<1><<<512, 512, 0, stream>>>(H16, H16, nullptr, Wg + 2 * WL, blockB + 2 * 2048, alpha);
    moie_gemm<1><<<512, 512, 0, stream>>>(H16, H16, nullptr, Wg + 3 * WL, blockB + 3 * 2048, alpha);
    moie_gemm<2><<<512, 512, 0, stream>>>(H16, nullptr, out, Wg + 4 * WL, outB,              alpha);
}